// Round 2
// baseline (1200.760 us; speedup 1.0000x reference)
//
#include <hip/hip_runtime.h>
#include <math.h>

#define CDIM 256
#define NE   1024
#define HW   4096            // 64*64
#define NB   16
#define ZQ_SIZE (NB*CDIM*HW) // 16777216

#define TB    64             // tokens per block (one per lane)
#define JN    16             // codes per j-tile (per wave)
#define JT_W  16             // j-tiles per wave (256 codes / JN)
#define ZS_LD 260            // padded z-row stride in floats (4-aligned, bank-spread)

// squared value with contraction blocked (replicates numpy's mul-then-add)
__device__ __forceinline__ float sq_nofma(float v) {
    float v2 = v * v;
    asm volatile("" : "+v"(v2));
    return v2;
}

// numpy pairwise_sum of 256 squared elements:
// split 128+128; each 128-block uses 8 accumulators then pairwise combine.
template <typename F>
__device__ __forceinline__ float pairwise256_sq(F get) {
    float total = 0.0f;
    #pragma unroll
    for (int h = 0; h < 2; ++h) {
        float r[8];
        #pragma unroll
        for (int j = 0; j < 8; ++j) r[j] = sq_nofma(get(h * 128 + j));
        #pragma unroll
        for (int i = 8; i < 128; i += 8) {
            #pragma unroll
            for (int j = 0; j < 8; ++j) r[j] += sq_nofma(get(h * 128 + i + j));
        }
        float s = ((r[0] + r[1]) + (r[2] + r[3])) + ((r[4] + r[5]) + (r[6] + r[7]));
        total = (h == 0) ? s : (total + s);
    }
    return total;
}

// ||emb_j||^2 for all 1024 codes -> ws
__global__ __launch_bounds__(256) void ee_kernel(const float* __restrict__ emb,
                                                 float* __restrict__ ee) {
    int j = blockIdx.x * 256 + threadIdx.x;
    const float* row = emb + (size_t)j * CDIM;
    ee[j] = pairwise256_sq([&](int i) { return row[i]; });
}

__global__ __launch_bounds__(256, 2) void vq_kernel(const float* __restrict__ z,
                                                    const float* __restrict__ emb,
                                                    const float* __restrict__ ee,
                                                    float* __restrict__ out) {
    __shared__ float zs[TB][ZS_LD];   // 66.5 KB, token-major z tile
    __shared__ float zzs[TB];
    __shared__ float red_d[4][TB];
    __shared__ int   red_j[4][TB];
    __shared__ int   bestj_s[TB];

    const int tid  = threadIdx.x;
    const int lane = tid & 63;
    const int wv   = __builtin_amdgcn_readfirstlane(tid >> 6); // wave id 0..3 (SGPR)
    const int b    = blockIdx.x >> 6;          // 64 hw-tiles per batch
    const int hw0  = (blockIdx.x & 63) << 6;   // *TB

    // ---- stage z tile: zs[t][c], t = lane, wave wv covers c ≡ wv (mod 4) ----
    {
        const float* zb = z + (size_t)b * CDIM * HW + hw0;
        #pragma unroll 4
        for (int it = 0; it < 64; ++it) {
            int c = it * 4 + wv;
            zs[lane][c] = zb[(size_t)c * HW + lane];   // coalesced 256B per wave
        }
    }
    __syncthreads();

    // ---- ||z||^2 per token, numpy pairwise order ----
    if (tid < TB) {
        zzs[tid] = pairwise256_sq([&](int i) { return zs[tid][i]; });
    }
    __syncthreads();

    const float zz = zzs[lane];
    float bd = INFINITY;
    int   bj = NE;

    // wave wv scans codes [wv*256, wv*256+256) in ascending order
    const int wj0 = wv << 8;
    for (int jt = 0; jt < JT_W; ++jt) {
        const int j0 = wj0 + jt * JN;
        float acc[JN];
        #pragma unroll
        for (int jj = 0; jj < JN; ++jj) acc[jj] = 0.0f;

        const float* ebase = emb + (size_t)j0 * CDIM;   // wave-uniform
        #pragma unroll 2
        for (int kc = 0; kc < CDIM / 4; ++kc) {
            float4 a = *reinterpret_cast<const float4*>(&zs[lane][kc * 4]);
            #pragma unroll
            for (int jj = 0; jj < JN; ++jj) {
                // wave-uniform address -> s_load_dwordx4 into SGPRs
                float4 bv = *reinterpret_cast<const float4*>(ebase + jj * CDIM + kc * 4);
                acc[jj] = fmaf(a.x, bv.x, acc[jj]);
                acc[jj] = fmaf(a.y, bv.y, acc[jj]);
                acc[jj] = fmaf(a.z, bv.z, acc[jj]);
                acc[jj] = fmaf(a.w, bv.w, acc[jj]);
            }
        }

        // d = (zz + ee) - 2*dot; ascending-j scan, strict <
        #pragma unroll
        for (int jj = 0; jj < JN; ++jj) {
            float t1 = zz + ee[j0 + jj];     // ee load is wave-uniform too
            float d  = t1 - 2.0f * acc[jj];
            if (d < bd) { bd = d; bj = j0 + jj; }
        }
    }

    // ---- cross-wave reduce (4 candidates per token; wave ranges ascending,
    //      so on ties keep the earlier wave = lower j) ----
    red_d[wv][lane] = bd;
    red_j[wv][lane] = bj;
    __syncthreads();

    if (tid < TB) {
        float d = red_d[0][tid];
        int   j = red_j[0][tid];
        #pragma unroll
        for (int w2 = 1; w2 < 4; ++w2) {
            float od = red_d[w2][tid];
            int   oj = red_j[w2][tid];
            if (od < d) { d = od; j = oj; }
        }
        bestj_s[tid] = j;
        out[(size_t)ZQ_SIZE + (size_t)b * HW + hw0 + tid] = (float)j;
    }
    __syncthreads();

    // ---- write z_q in NCHW: out[b][c][hw0+t] = emb[bestj][c] ----
    {
        const int jb = bestj_s[lane];
        const float* er = emb + (size_t)jb * CDIM;
        float* ob = out + (size_t)b * CDIM * HW + hw0 + lane;
        #pragma unroll 4
        for (int c = wv; c < CDIM; c += 4) {
            ob[(size_t)c * HW] = er[c];     // coalesced 256B per wave
        }
    }
}

extern "C" void kernel_launch(void* const* d_in, const int* in_sizes, int n_in,
                              void* d_out, int out_size, void* d_ws, size_t ws_size,
                              hipStream_t stream) {
    const float* z   = (const float*)d_in[0];
    const float* emb = (const float*)d_in[1];
    float* ee  = (float*)d_ws;   // 1024 floats
    float* out = (float*)d_out;

    ee_kernel<<<dim3(NE / 256), dim3(256), 0, stream>>>(emb, ee);
    vq_kernel<<<dim3((NB * HW) / TB), dim3(256), 0, stream>>>(z, emb, ee, out);
}

// Round 4
// 538.851 us; speedup vs baseline: 2.2284x; 2.2284x over previous
//
#include <hip/hip_runtime.h>
#include <math.h>

#define CDIM 256
#define NE   1024
#define HW   4096            // 64*64
#define NB   16
#define ZQ_SIZE (NB*CDIM*HW) // 16777216

typedef unsigned short ushort_t;
typedef __attribute__((ext_vector_type(8))) __bf16 bf16x8;
typedef __attribute__((ext_vector_type(8))) unsigned short u16x8;
typedef __attribute__((ext_vector_type(4))) float f32x4;

// 15.8 sigma of the pairwise d-hat error (std ~3.8e-5, dominated by the
// dropped 2*sum z*(e - bf16(e)) term with bf16's 7-bit mantissa).
#define MARGIN 6.0e-4f

// ws layout
#define WS_EE    0
#define WS_ZZ    4096
#define WS_CNT   266240
#define WS_LIST  266496
#define WS_EHP   528640
#define WS_NEEDED 1052928

// ---------------- shared helpers (validated in round 1) ----------------
__device__ __forceinline__ float sq_nofma(float v) {
    float v2 = v * v;
    asm volatile("" : "+v"(v2));
    return v2;
}

template <typename F>
__device__ __forceinline__ float pairwise256_sq(F get) {
    float total = 0.0f;
    #pragma unroll
    for (int h = 0; h < 2; ++h) {
        float r[8];
        #pragma unroll
        for (int j = 0; j < 8; ++j) r[j] = sq_nofma(get(h * 128 + j));
        #pragma unroll
        for (int i = 8; i < 128; i += 8) {
            #pragma unroll
            for (int j = 0; j < 8; ++j) r[j] += sq_nofma(get(h * 128 + i + j));
        }
        float s = ((r[0] + r[1]) + (r[2] + r[3])) + ((r[4] + r[5]) + (r[6] + r[7]));
        total = (h == 0) ? s : (total + s);
    }
    return total;
}

__device__ __forceinline__ unsigned short f2bf_rne(float v) {
    unsigned u = __float_as_uint(v);
    return (unsigned short)((u + 0x7FFFu + ((u >> 16) & 1u)) >> 16);
}
__device__ __forceinline__ float bf2f(unsigned short h) {
    return __uint_as_float(((unsigned)h) << 16);
}

// ||emb_j||^2 for all 1024 codes -> ws (round-1 exact)
__global__ __launch_bounds__(256) void ee_kernel(const float* __restrict__ emb,
                                                 float* __restrict__ ee) {
    int j = blockIdx.x * 256 + threadIdx.x;
    const float* row = emb + (size_t)j * CDIM;
    ee[j] = pairwise256_sq([&](int i) { return row[i]; });
}

// emb -> bf16 plane (RNE); also zeroes the flag counter
__global__ __launch_bounds__(256) void eh_kernel(const float* __restrict__ emb,
                                                 ushort_t* __restrict__ ehp,
                                                 int* __restrict__ cnt) {
    if (blockIdx.x == 0 && threadIdx.x == 0) *cnt = 0;
    int row = blockIdx.x * 4 + (threadIdx.x >> 6);
    int c   = (threadIdx.x & 63) * 4;
    float4 v = *reinterpret_cast<const float4*>(&emb[(size_t)row * CDIM + c]);
    unsigned w0 = (unsigned)f2bf_rne(v.x) | ((unsigned)f2bf_rne(v.y) << 16);
    unsigned w1 = (unsigned)f2bf_rne(v.z) | ((unsigned)f2bf_rne(v.w) << 16);
    uint2 w = {w0, w1};
    *reinterpret_cast<uint2*>(&ehp[(size_t)row * CDIM + c]) = w;
}

// ---------------- main MFMA kernel ----------------
__global__ __launch_bounds__(256, 1) void vq_main(const float* __restrict__ z,
                                                  const float* __restrict__ emb,
                                                  const ushort_t* __restrict__ ehp,
                                                  const float* __restrict__ eew,
                                                  float* __restrict__ zzw,
                                                  int* __restrict__ cnt,
                                                  int* __restrict__ list,
                                                  float* __restrict__ out) {
    __shared__ __align__(16) char arena[138752];
    char* zhB  = arena;                 // 64 x 256 bf16, swizzled   (32768 B)
    char* zlB  = arena + 32768;         // 64 x 256 bf16, swizzled   (32768 B)
    char* ehsB = arena + 65536;         // 2 x 256 x 64 bf16, swz    (65536 B)
    float* eel = (float*)(arena + 131072); // 1024 f32
    float* zzs = (float*)(arena + 135168); // 64 f32
    float* rd1 = (float*)(arena + 135424); // [4][64]
    int*   rj1 = (int*)  (arena + 136448);
    float* rd2 = (float*)(arena + 137472);
    int*   rbj = (int*)  (arena + 138496); // 64

    const int tid  = threadIdx.x;
    const int lane = tid & 63;
    const int wn   = tid >> 6;
    const int b    = blockIdx.x >> 6;
    const int hw0  = (blockIdx.x & 63) << 6;
    const float* zb = z + (size_t)b * CDIM * HW + hw0;

    // ---- phase 0: stage z planes (split bf16) + ee into LDS ----
    {
        const int tok = tid & 63;
        const int kq  = tid >> 6;
        #pragma unroll 4
        for (int i = 0; i < 32; ++i) {
            int k = (kq << 1) + (i << 3);        // even
            float v0 = zb[(size_t)k * HW + tok];
            float v1 = zb[(size_t)(k + 1) * HW + tok];
            unsigned short h0 = f2bf_rne(v0), h1 = f2bf_rne(v1);
            float lo0 = v0 - bf2f(h0), lo1 = v1 - bf2f(h1);
            unsigned short g0 = f2bf_rne(lo0), g1 = f2bf_rne(lo1);
            int byteoff = tok * 512 + ((k * 2) ^ ((tok & 7) << 4));
            *(unsigned*)(zhB + byteoff) = (unsigned)h0 | ((unsigned)h1 << 16);
            *(unsigned*)(zlB + byteoff) = (unsigned)g0 | ((unsigned)g1 << 16);
        }
        #pragma unroll
        for (int i = 0; i < 4; ++i) eel[tid + 256 * i] = eew[tid + 256 * i];
    }
    __syncthreads();

    // ---- phase 1: zz (exact numpy-pairwise) + stage E slab 0 ----
    if (tid < 64) {
        float s = pairwise256_sq([&](int i) { return zb[(size_t)i * HW + tid]; });
        zzs[tid] = s;
        zzw[(size_t)b * HW + hw0 + tid] = s;
    }
    {
        const int a  = tid & 7;
        const int c0 = tid >> 3;
        #pragma unroll
        for (int p = 0; p < 8; ++p) {
            int cg = c0 + (p << 5);
            u16x8 v = *(const u16x8*)(ehp + (size_t)cg * CDIM + (a << 3));
            *(u16x8*)(ehsB + cg * 128 + ((a * 16) ^ ((cg & 7) << 4))) = v;
        }
    }
    __syncthreads();

    // per-lane token squared norms (16 tokens per lane)
    float zz4[4][4];
    const int lr  = lane & 15;
    const int lg  = lane >> 4;
    const int lkb = lg << 3;
    #pragma unroll
    for (int m = 0; m < 4; ++m)
        #pragma unroll
        for (int r = 0; r < 4; ++r)
            zz4[m][r] = zzs[m * 16 + (lg << 2) + r];

    f32x4 acc[4][4];
    float sd1[4][4], sd2[4][4];
    int   sj1[4][4];
    #pragma unroll
    for (int m = 0; m < 4; ++m)
        #pragma unroll
        for (int r = 0; r < 4; ++r) { sd1[m][r] = INFINITY; sd2[m][r] = INFINITY; sj1[m][r] = NE; }

    const int a7 = tid & 7;
    const int c0 = tid >> 3;

    for (int s = 0; s < 16; ++s) {
        const int chunk = s >> 2, kb = s & 3;
        const int buf = (s & 1) << 15;
        if (kb == 0) {
            #pragma unroll
            for (int m = 0; m < 4; ++m)
                #pragma unroll
                for (int n = 0; n < 4; ++n) acc[m][n] = (f32x4){0.f, 0.f, 0.f, 0.f};
        }
        // prefetch next slab to regs (T14)
        u16x8 pf[8];
        if (s < 15) {
            const int sn = s + 1;
            const ushort_t* srcb = ehp + ((size_t)((sn >> 2) * 256)) * CDIM + (sn & 3) * 64 + (a7 << 3);
            #pragma unroll
            for (int p = 0; p < 8; ++p)
                pf[p] = *(const u16x8*)(srcb + (size_t)(c0 + (p << 5)) * CDIM);
        }
        // compute: 2 k-steps of 32
        #pragma unroll
        for (int ks = 0; ks < 2; ++ks) {
            const int ke = (kb << 6) + (ks << 5) + lkb;      // global k of frag
            const int kl = (ks << 5) + lkb;                  // k within slab
            bf16x8 ah[4], al[4], bh[4];
            #pragma unroll
            for (int m = 0; m < 4; ++m) {
                int row = m * 16 + lr;
                int off = row * 512 + ((ke * 2) ^ ((row & 7) << 4));
                ah[m] = __builtin_bit_cast(bf16x8, *(const u16x8*)(zhB + off));
                al[m] = __builtin_bit_cast(bf16x8, *(const u16x8*)(zlB + off));
            }
            #pragma unroll
            for (int n = 0; n < 4; ++n) {
                int code = wn * 64 + n * 16 + lr;
                bh[n] = __builtin_bit_cast(bf16x8,
                    *(const u16x8*)(ehsB + buf + code * 128 + ((kl * 2) ^ ((code & 7) << 4))));
            }
            #pragma unroll
            for (int m = 0; m < 4; ++m)
                #pragma unroll
                for (int n = 0; n < 4; ++n) {
                    acc[m][n] = __builtin_amdgcn_mfma_f32_16x16x32_bf16(ah[m], bh[n], acc[m][n], 0, 0, 0);
                    acc[m][n] = __builtin_amdgcn_mfma_f32_16x16x32_bf16(al[m], bh[n], acc[m][n], 0, 0, 0);
                }
        }
        // epilogue per chunk: d = fl(fl(zz+ee) - fl(2*dot_hat)), track top-2
        if (kb == 3) {
            #pragma unroll
            for (int n = 0; n < 4; ++n) {
                int code = (chunk << 8) + (wn << 6) + (n << 4) + lr;
                float eev = eel[code];
                #pragma unroll
                for (int m = 0; m < 4; ++m)
                    #pragma unroll
                    for (int r = 0; r < 4; ++r) {
                        float t1 = zz4[m][r] + eev;
                        float d  = t1 - 2.0f * acc[m][n][r];
                        bool lt1 = d < sd1[m][r];
                        bool lt2 = d < sd2[m][r];
                        sd2[m][r] = lt1 ? sd1[m][r] : (lt2 ? d : sd2[m][r]);
                        if (lt1) { sd1[m][r] = d; sj1[m][r] = code; }
                    }
            }
        }
        // write prefetched slab into the other buffer
        if (s < 15) {
            const int nbuf = buf ^ 32768;
            #pragma unroll
            for (int p = 0; p < 8; ++p) {
                int cg = c0 + (p << 5);
                *(u16x8*)(ehsB + nbuf + cg * 128 + ((a7 * 16) ^ ((cg & 7) << 4))) = pf[p];
            }
        }
        __syncthreads();
    }

    // ---- cross-lane top-2 merge over the 16 code-lanes ----
    #pragma unroll
    for (int off = 1; off <= 8; off <<= 1) {
        #pragma unroll
        for (int m = 0; m < 4; ++m)
            #pragma unroll
            for (int r = 0; r < 4; ++r) {
                float od1 = __shfl_xor(sd1[m][r], off);
                int   oj1 = __shfl_xor(sj1[m][r], off);
                float od2 = __shfl_xor(sd2[m][r], off);
                float nd2 = fminf(fmaxf(sd1[m][r], od1), fminf(sd2[m][r], od2));
                bool tk = (od1 < sd1[m][r]) || (od1 == sd1[m][r] && oj1 < sj1[m][r]);
                if (tk) { sd1[m][r] = od1; sj1[m][r] = oj1; }
                sd2[m][r] = nd2;
            }
    }
    if (lr == 0) {
        #pragma unroll
        for (int m = 0; m < 4; ++m)
            #pragma unroll
            for (int r = 0; r < 4; ++r) {
                int tok = m * 16 + (lg << 2) + r;
                rd1[wn * 64 + tok] = sd1[m][r];
                rj1[wn * 64 + tok] = sj1[m][r];
                rd2[wn * 64 + tok] = sd2[m][r];
            }
    }
    __syncthreads();

    // ---- combine 4 waves, decide, emit idx / flag ----
    if (tid < 64) {
        float d1f = rd1[tid]; int j1f = rj1[tid]; float d2f = rd2[tid];
        #pragma unroll
        for (int w = 1; w < 4; ++w) {
            float od1 = rd1[w * 64 + tid];
            int   oj1 = rj1[w * 64 + tid];
            float od2 = rd2[w * 64 + tid];
            float nd2 = fminf(fmaxf(d1f, od1), fminf(d2f, od2));
            bool tk = (od1 < d1f) || (od1 == d1f && oj1 < j1f);
            if (tk) { d1f = od1; j1f = oj1; }
            d2f = nd2;
        }
        rbj[tid] = j1f;
        int gtok = b * HW + hw0 + tid;
        out[(size_t)ZQ_SIZE + gtok] = (float)j1f;
        if (!(d2f - d1f > MARGIN)) {
            int slot = atomicAdd(cnt, 1);
            list[slot] = gtok;
        }
    }
    __syncthreads();

    // ---- z_q: gather emb rows -> LDS (aliases zh/zl/ehs) -> coalesced NCHW ----
    float* zq_st = (float*)arena;   // [64][261]
    {
        int row = tid >> 2, sub = tid & 3;
        int j = rbj[row];
        const float* er = emb + (size_t)j * CDIM;
        #pragma unroll
        for (int i = 0; i < 16; ++i) {
            int c = (sub << 2) + (i << 4);
            float4 v = *reinterpret_cast<const float4*>(er + c);
            zq_st[row * 261 + c + 0] = v.x;
            zq_st[row * 261 + c + 1] = v.y;
            zq_st[row * 261 + c + 2] = v.z;
            zq_st[row * 261 + c + 3] = v.w;
        }
    }
    __syncthreads();
    {
        int tok = tid & 63, cg = tid >> 6;
        float* ob = out + (size_t)b * CDIM * HW + hw0 + tok;
        #pragma unroll 4
        for (int i = 0; i < 64; ++i) {
            int c = (cg << 6) + i;
            ob[(size_t)c * HW] = zq_st[tok * 261 + c];
        }
    }
}

// ---------------- exact fp32 fallback for flagged tokens ----------------
__global__ __launch_bounds__(256) void vq_fallback(const float* __restrict__ z,
                                                   const float* __restrict__ emb,
                                                   const float* __restrict__ eew,
                                                   const float* __restrict__ zzw,
                                                   const int* __restrict__ cnt,
                                                   const int* __restrict__ list,
                                                   float* __restrict__ out) {
    __shared__ float elds[64][261];
    __shared__ float zrow[4][256];
    __shared__ int   toks[4];

    const int tid  = threadIdx.x;
    const int lane = tid & 63;
    const int wv   = tid >> 6;
    const int nt   = *cnt;
    const int groups = (nt + 3) >> 2;

    for (int g = blockIdx.x; g < groups; g += gridDim.x) {
        if (tid < 4) toks[tid] = (g * 4 + tid < nt) ? list[g * 4 + tid] : -1;
        __syncthreads();
        const int gt = toks[wv];
        const bool act = gt >= 0;
        const int tb = act ? (gt >> 12) : 0;
        const int thw = act ? (gt & 4095) : 0;
        if (act) {
            #pragma unroll
            for (int i = 0; i < 4; ++i)
                zrow[wv][i * 64 + lane] = z[(size_t)tb * CDIM * HW + (size_t)(i * 64 + lane) * HW + thw];
        }
        const float zz = act ? zzw[gt] : 0.0f;
        float d1 = INFINITY; int j1 = NE;

        for (int c = 0; c < 16; ++c) {
            __syncthreads();
            {
                int row = tid >> 2, sub = tid & 3;
                #pragma unroll
                for (int i = 0; i < 16; ++i) {
                    int col = (sub << 2) + (i << 4);
                    float4 v = *reinterpret_cast<const float4*>(
                        &emb[(size_t)(c * 64 + row) * CDIM + col]);
                    elds[row][col + 0] = v.x;
                    elds[row][col + 1] = v.y;
                    elds[row][col + 2] = v.z;
                    elds[row][col + 3] = v.w;
                }
            }
            __syncthreads();
            if (act) {
                float acc = 0.0f;
                #pragma unroll 8
                for (int k = 0; k < 256; ++k)
                    acc = fmaf(zrow[wv][k], elds[lane][k], acc);
                int j = c * 64 + lane;
                float t1 = zz + eew[j];
                float d  = t1 - 2.0f * acc;
                if (d < d1) { d1 = d; j1 = j; }
            }
        }
        // lexicographic wave reduce
        #pragma unroll
        for (int off = 1; off <= 32; off <<= 1) {
            float od = __shfl_xor(d1, off);
            int   oj = __shfl_xor(j1, off);
            if (od < d1 || (od == d1 && oj < j1)) { d1 = od; j1 = oj; }
        }
        if (act) {
            if (lane == 0) out[(size_t)ZQ_SIZE + gt] = (float)j1;
            #pragma unroll
            for (int i = 0; i < 4; ++i) {
                int cc = i * 64 + lane;
                out[(size_t)tb * CDIM * HW + (size_t)cc * HW + thw] = emb[(size_t)j1 * CDIM + cc];
            }
        }
        __syncthreads();
    }
}

// ---------------- legacy round-1 kernel (used only if ws too small) ----------------
#define BM 32
#define BN 256
#define BK 16
__global__ __launch_bounds__(256, 3) void vq_legacy(const float* __restrict__ z,
                                                    const float* __restrict__ emb,
                                                    const float* __restrict__ ee,
                                                    float* __restrict__ out) {
    __shared__ float zs[CDIM][BM];
    __shared__ float es[BK][BN];
    __shared__ float ees[BN];
    __shared__ float zzs[BM];
    __shared__ float red_d[4][BM];
    __shared__ int   red_j[4][BM];
    __shared__ int   bestj_s[BM];

    const int tid = threadIdx.x;
    const int b   = blockIdx.x >> 7;
    const int hw0 = (blockIdx.x & 127) << 5;
    const int ti  = tid & 7;
    const int tj  = tid >> 3;
    const int tm0 = ti << 2;
    const int jc0 = tj << 3;
    {
        const float* zb = z + (size_t)b * CDIM * HW + hw0;
        #pragma unroll
        for (int r = 0; r < 8; ++r) {
            int f4 = (r << 8) + tid;
            int c  = f4 >> 3;
            int t4 = (f4 & 7) << 2;
            float4 v = *reinterpret_cast<const float4*>(zb + (size_t)c * HW + t4);
            *reinterpret_cast<float4*>(&zs[c][t4]) = v;
        }
    }
    __syncthreads();
    if (tid < BM) zzs[tid] = pairwise256_sq([&](int i) { return zs[i][tid]; });
    __syncthreads();
    float bd[4]; int bj[4];
    #pragma unroll
    for (int i = 0; i < 4; ++i) { bd[i] = INFINITY; bj[i] = NE; }
    for (int jt = 0; jt < NE / BN; ++jt) {
        const int j0 = jt * BN;
        float acc[4][8];
        #pragma unroll
        for (int i = 0; i < 4; ++i)
            #pragma unroll
            for (int jj = 0; jj < 8; ++jj) acc[i][jj] = 0.0f;
        for (int kt = 0; kt < CDIM / BK; ++kt) {
            __syncthreads();
            #pragma unroll
            for (int r = 0; r < 4; ++r) {
                int f4 = (r << 8) + tid;
                int jj = f4 >> 2;
                int c4 = (f4 & 3) << 2;
                float4 v = *reinterpret_cast<const float4*>(
                    emb + (size_t)(j0 + jj) * CDIM + kt * BK + c4);
                es[c4 + 0][jj] = v.x; es[c4 + 1][jj] = v.y;
                es[c4 + 2][jj] = v.z; es[c4 + 3][jj] = v.w;
            }
            if (kt == 0 && tid < BN) ees[tid] = ee[j0 + tid];
            __syncthreads();
            #pragma unroll
            for (int k = 0; k < BK; ++k) {
                float4 av  = *reinterpret_cast<const float4*>(&zs[kt * BK + k][tm0]);
                float4 bv0 = *reinterpret_cast<const float4*>(&es[k][jc0]);
                float4 bv1 = *reinterpret_cast<const float4*>(&es[k][jc0 + 4]);
                float bb[8] = {bv0.x, bv0.y, bv0.z, bv0.w, bv1.x, bv1.y, bv1.z, bv1.w};
                #pragma unroll
                for (int jj = 0; jj < 8; ++jj) {
                    acc[0][jj] = fmaf(av.x, bb[jj], acc[0][jj]);
                    acc[1][jj] = fmaf(av.y, bb[jj], acc[1][jj]);
                    acc[2][jj] = fmaf(av.z, bb[jj], acc[2][jj]);
                    acc[3][jj] = fmaf(av.w, bb[jj], acc[3][jj]);
                }
            }
        }
        #pragma unroll
        for (int i = 0; i < 4; ++i) {
            float zzv = zzs[tm0 + i];
            #pragma unroll
            for (int jj = 0; jj < 8; ++jj) {
                float t1 = zzv + ees[jc0 + jj];
                float d  = t1 - 2.0f * acc[i][jj];
                if (d < bd[i]) { bd[i] = d; bj[i] = j0 + jc0 + jj; }
            }
        }
    }
    #pragma unroll
    for (int off = 8; off <= 32; off <<= 1) {
        #pragma unroll
        for (int i = 0; i < 4; ++i) {
            float od = __shfl_xor(bd[i], off);
            int   oj = __shfl_xor(bj[i], off);
            if (od < bd[i] || (od == bd[i] && oj < bj[i])) { bd[i] = od; bj[i] = oj; }
        }
    }
    {
        const int lane = tid & 63;
        const int w    = tid >> 6;
        if (lane < 8) {
            #pragma unroll
            for (int i = 0; i < 4; ++i) {
                red_d[w][lane * 4 + i] = bd[i];
                red_j[w][lane * 4 + i] = bj[i];
            }
        }
    }
    __syncthreads();
    if (tid < BM) {
        float d = red_d[0][tid]; int j = red_j[0][tid];
        #pragma unroll
        for (int w2 = 1; w2 < 4; ++w2) {
            float od = red_d[w2][tid]; int oj = red_j[w2][tid];
            if (od < d || (od == d && oj < j)) { d = od; j = oj; }
        }
        bestj_s[tid] = j;
        out[(size_t)ZQ_SIZE + (size_t)b * HW + hw0 + tid] = (float)j;
    }
    __syncthreads();
    {
        const int t  = tid & 31;
        const int c0 = tid >> 5;
        const int jb = bestj_s[t];
        const float* er = emb + (size_t)jb * CDIM;
        float* ob = out + (size_t)b * CDIM * HW + hw0 + t;
        #pragma unroll
        for (int c = c0; c < CDIM; c += 8) ob[(size_t)c * HW] = er[c];
    }
}

extern "C" void kernel_launch(void* const* d_in, const int* in_sizes, int n_in,
                              void* d_out, int out_size, void* d_ws, size_t ws_size,
                              hipStream_t stream) {
    const float* z   = (const float*)d_in[0];
    const float* emb = (const float*)d_in[1];
    float* out = (float*)d_out;
    char*  ws  = (char*)d_ws;

    float*    ee   = (float*)(ws + WS_EE);
    float*    zzw  = (float*)(ws + WS_ZZ);
    int*      cnt  = (int*)  (ws + WS_CNT);
    int*      list = (int*)  (ws + WS_LIST);
    ushort_t* ehp  = (ushort_t*)(ws + WS_EHP);

    if (ws_size >= (size_t)WS_NEEDED) {
        ee_kernel<<<dim3(NE / 256), dim3(256), 0, stream>>>(emb, ee);
        eh_kernel<<<dim3(256), dim3(256), 0, stream>>>(emb, ehp, cnt);
        vq_main<<<dim3((NB * HW) / 64), dim3(256), 0, stream>>>(z, emb, ehp, ee, zzw,
                                                                cnt, list, out);
        vq_fallback<<<dim3(512), dim3(256), 0, stream>>>(z, emb, ee, zzw, cnt, list, out);
    } else {
        ee_kernel<<<dim3(NE / 256), dim3(256), 0, stream>>>(emb, ee);
        vq_legacy<<<dim3((NB * HW) / BM), dim3(256), 0, stream>>>(z, emb, ee, out);
    }
}

// Round 5
// 355.876 us; speedup vs baseline: 3.3741x; 1.5142x over previous
//
#include <hip/hip_runtime.h>
#include <math.h>

#define CDIM 256
#define NE   1024
#define HW   4096            // 64*64
#define NB   16
#define ZQ_SIZE (NB*CDIM*HW) // 16777216

typedef unsigned short ushort_t;
typedef __attribute__((ext_vector_type(8))) __bf16 bf16x8;
typedef __attribute__((ext_vector_type(8))) unsigned short u16x8;
typedef __attribute__((ext_vector_type(4))) float f32x4;

// Residual of the 3-pass split (zh*eh + zl*eh + zh*el): sigma ~1e-7,
// adversarial worst ~3e-5. 4e-5 = ~400 sigma and > worst-case bound.
#define MARGIN 4.0e-5f

// ws layout (bytes)
#define WS_EE    0           // 1024 f32
#define WS_ZZ    4096        // 65536 f32
#define WS_CNT   266240      // 1 int (+pad)
#define WS_LIST  266496      // 65536 int (== total tokens, can't overflow)
#define WS_NEEDED 528640

// ---------------- helpers (validated rounds 1-4) ----------------
__device__ __forceinline__ float sq_nofma(float v) {
    float v2 = v * v;
    asm volatile("" : "+v"(v2));
    return v2;
}

template <typename F>
__device__ __forceinline__ float pairwise256_sq(F get) {
    float total = 0.0f;
    #pragma unroll
    for (int h = 0; h < 2; ++h) {
        float r[8];
        #pragma unroll
        for (int j = 0; j < 8; ++j) r[j] = sq_nofma(get(h * 128 + j));
        #pragma unroll
        for (int i = 8; i < 128; i += 8) {
            #pragma unroll
            for (int j = 0; j < 8; ++j) r[j] += sq_nofma(get(h * 128 + i + j));
        }
        float s = ((r[0] + r[1]) + (r[2] + r[3])) + ((r[4] + r[5]) + (r[6] + r[7]));
        total = (h == 0) ? s : (total + s);
    }
    return total;
}

// one 128-elem half of the numpy pairwise sum (exact same op order)
template <typename F>
__device__ __forceinline__ float pairwise128_sq(F get) {
    float r[8];
    #pragma unroll
    for (int j = 0; j < 8; ++j) r[j] = sq_nofma(get(j));
    #pragma unroll
    for (int i = 8; i < 128; i += 8) {
        #pragma unroll
        for (int j = 0; j < 8; ++j) r[j] += sq_nofma(get(i + j));
    }
    return ((r[0] + r[1]) + (r[2] + r[3])) + ((r[4] + r[5]) + (r[6] + r[7]));
}

__device__ __forceinline__ ushort_t f2bf_rne(float v) {
    unsigned u = __float_as_uint(v);
    return (ushort_t)((u + 0x7FFFu + ((u >> 16) & 1u)) >> 16);
}
__device__ __forceinline__ float bf2f(ushort_t h) {
    return __uint_as_float(((unsigned)h) << 16);
}
__device__ __forceinline__ unsigned cvtpk_bf16(float lo, float hi) {
    unsigned r;
    asm volatile("v_cvt_pk_bf16_f32 %0, %1, %2" : "=v"(r) : "v"(lo), "v"(hi));
    return r;
}
__device__ __forceinline__ float pk_lo_f(unsigned p) { return __uint_as_float(p << 16); }
__device__ __forceinline__ float pk_hi_f(unsigned p) { return __uint_as_float(p & 0xffff0000u); }

// ||emb_j||^2 -> ws; also zero flag counter
__global__ __launch_bounds__(256) void ee_kernel(const float* __restrict__ emb,
                                                 float* __restrict__ ee,
                                                 int* __restrict__ cnt) {
    if (blockIdx.x == 0 && threadIdx.x == 0) *cnt = 0;
    int j = blockIdx.x * 256 + threadIdx.x;
    const float* row = emb + (size_t)j * CDIM;
    ee[j] = pairwise256_sq([&](int i) { return row[i]; });
}

// ---------------- main MFMA kernel: 512 thr, 8 waves, 64 tokens ----------------
__global__ __launch_bounds__(512, 2) void vq_main(const float* __restrict__ z,
                                                  const float* __restrict__ emb,
                                                  const float* __restrict__ eew,
                                                  float* __restrict__ zzw,
                                                  int* __restrict__ cnt,
                                                  int* __restrict__ list,
                                                  float* __restrict__ out) {
    __shared__ __align__(16) char arena[142336];
    char* zhB = arena;                      // 64x256 bf16 swz      32768
    char* zlB = arena + 32768;              //                      32768
    char* ehB = arena + 65536;              // 256x64 bf16 swz      32768
    char* elB = arena + 98304;              //                      32768
    float* eel = (float*)(arena + 131072);  // 1024 f32
    float* zzp = (float*)(arena + 135168);  // 64x2 f32 halves
    float* rd1 = (float*)(arena + 135680);  // [8][64]
    int*   rj1 = (int*)  (arena + 137728);
    float* rd2 = (float*)(arena + 139776);
    int*   rbj = (int*)  (arena + 141824);  // 64

    const int tid  = threadIdx.x;
    const int lane = tid & 63;
    const int wn   = tid >> 6;               // wave 0..7
    const int b    = blockIdx.x >> 6;
    const int hw0  = (blockIdx.x & 63) << 6;
    const float* zb = z + (size_t)b * CDIM * HW + hw0;

    // ---- phase 0: z split-staging, eel, zz halves, slab-0 prefetch ----
    {
        const int tok = tid & 63;
        const int kq  = tid >> 6;
        #pragma unroll
        for (int i = 0; i < 16; ++i) {
            int k = kq * 2 + i * 16;
            float v0 = zb[(size_t)k * HW + tok];
            float v1 = zb[(size_t)(k + 1) * HW + tok];
            ushort_t h0 = f2bf_rne(v0), h1 = f2bf_rne(v1);
            float l0 = v0 - bf2f(h0), l1 = v1 - bf2f(h1);
            ushort_t g0 = f2bf_rne(l0), g1 = f2bf_rne(l1);
            int off = tok * 512 + ((k * 2) ^ ((tok & 7) << 4));
            *(unsigned*)(zhB + off) = (unsigned)h0 | ((unsigned)h1 << 16);
            *(unsigned*)(zlB + off) = (unsigned)g0 | ((unsigned)g1 << 16);
        }
        eel[tid]       = eew[tid];
        eel[tid + 512] = eew[tid + 512];
    }
    if (tid < 128) {  // zz: 2 threads per token (independent numpy halves)
        int tok = tid >> 1, h = tid & 1;
        zzp[tok * 2 + h] = pairwise128_sq([&](int i) {
            return zb[(size_t)(h * 128 + i) * HW + tok];
        });
    }

    const int scg = tid >> 1;             // staging code row 0..255
    const int skh = (tid & 1) << 5;       // staging k-half 0/32
    float4 pf[8];
    {
        const float* src = emb + (size_t)scg * CDIM + skh;  // slab (chunk0,kb0)
        #pragma unroll
        for (int q = 0; q < 8; ++q) pf[q] = *reinterpret_cast<const float4*>(src + q * 4);
    }

    const int lr  = lane & 15;
    const int lg  = lane >> 4;
    const int lkb = lg << 3;

    f32x4 acc[4][2];
    float sd1[4][4], sd2[4][4];
    int   sj1[4][4];
    float zz4[4][4];
    #pragma unroll
    for (int m = 0; m < 4; ++m)
        #pragma unroll
        for (int r = 0; r < 4; ++r) { sd1[m][r] = INFINITY; sd2[m][r] = INFINITY; sj1[m][r] = NE; }

    for (int s = 0; s < 16; ++s) {
        const int chunk = s >> 2, kb = s & 3;
        __syncthreads();   // z/zz ready (s=0) or previous slab fully consumed
        if (s == 0) {
            #pragma unroll
            for (int m = 0; m < 4; ++m)
                #pragma unroll
                for (int r = 0; r < 4; ++r) {
                    int t = m * 16 + lg * 4 + r;
                    zz4[m][r] = zzp[2 * t] + zzp[2 * t + 1];
                }
        }
        // convert prefetched fp32 -> eh/el bf16 planes, write slab
        #pragma unroll
        for (int q = 0; q < 4; ++q) {
            float4 va = pf[2 * q], vb = pf[2 * q + 1];
            unsigned e0 = cvtpk_bf16(va.x, va.y), e1 = cvtpk_bf16(va.z, va.w);
            unsigned e2 = cvtpk_bf16(vb.x, vb.y), e3 = cvtpk_bf16(vb.z, vb.w);
            float r0 = va.x - pk_lo_f(e0), r1 = va.y - pk_hi_f(e0);
            float r2 = va.z - pk_lo_f(e1), r3 = va.w - pk_hi_f(e1);
            float r4 = vb.x - pk_lo_f(e2), r5 = vb.y - pk_hi_f(e2);
            float r6 = vb.z - pk_lo_f(e3), r7 = vb.w - pk_hi_f(e3);
            unsigned f0 = cvtpk_bf16(r0, r1), f1 = cvtpk_bf16(r2, r3);
            unsigned f2 = cvtpk_bf16(r4, r5), f3 = cvtpk_bf16(r6, r7);
            int koff = ((skh + q * 8) * 2) ^ ((scg & 7) << 4);
            *reinterpret_cast<uint4*>(ehB + scg * 128 + koff) = (uint4){e0, e1, e2, e3};
            *reinterpret_cast<uint4*>(elB + scg * 128 + koff) = (uint4){f0, f1, f2, f3};
        }
        if (s < 15) {   // prefetch next slab (hidden under MFMA phase)
            const int sn = s + 1;
            const float* src = emb + ((size_t)((sn >> 2) * 256 + scg)) * CDIM + (sn & 3) * 64 + skh;
            #pragma unroll
            for (int q = 0; q < 8; ++q) pf[q] = *reinterpret_cast<const float4*>(src + q * 4);
        }
        if (kb == 0) {
            #pragma unroll
            for (int m = 0; m < 4; ++m)
                #pragma unroll
                for (int n = 0; n < 2; ++n) acc[m][n] = (f32x4){0.f, 0.f, 0.f, 0.f};
        }
        __syncthreads();   // slab ready

        #pragma unroll
        for (int ks = 0; ks < 2; ++ks) {
            const int kl = ks * 32 + lkb;            // k within slab
            const int ke = kb * 64 + kl;             // k within z row
            bf16x8 ah[4], al[4], bh[2], bl[2];
            #pragma unroll
            for (int m = 0; m < 4; ++m) {
                int row = m * 16 + lr;
                int off = row * 512 + ((ke * 2) ^ ((row & 7) << 4));
                ah[m] = __builtin_bit_cast(bf16x8, *(const u16x8*)(zhB + off));
                al[m] = __builtin_bit_cast(bf16x8, *(const u16x8*)(zlB + off));
            }
            #pragma unroll
            for (int n = 0; n < 2; ++n) {
                int code = wn * 32 + n * 16 + lr;
                int boff = code * 128 + ((kl * 2) ^ ((code & 7) << 4));
                bh[n] = __builtin_bit_cast(bf16x8, *(const u16x8*)(ehB + boff));
                bl[n] = __builtin_bit_cast(bf16x8, *(const u16x8*)(elB + boff));
            }
            #pragma unroll
            for (int m = 0; m < 4; ++m)
                #pragma unroll
                for (int n = 0; n < 2; ++n) {
                    acc[m][n] = __builtin_amdgcn_mfma_f32_16x16x32_bf16(ah[m], bh[n], acc[m][n], 0, 0, 0);
                    acc[m][n] = __builtin_amdgcn_mfma_f32_16x16x32_bf16(al[m], bh[n], acc[m][n], 0, 0, 0);
                    acc[m][n] = __builtin_amdgcn_mfma_f32_16x16x32_bf16(ah[m], bl[n], acc[m][n], 0, 0, 0);
                }
        }

        if (kb == 3) {   // chunk epilogue: d, top-2 (codes ascend over s,n)
            #pragma unroll
            for (int n = 0; n < 2; ++n) {
                int code = (chunk << 8) + (wn << 5) + (n << 4) + lr;
                float eev = eel[code];
                #pragma unroll
                for (int m = 0; m < 4; ++m)
                    #pragma unroll
                    for (int r = 0; r < 4; ++r) {
                        float t1 = zz4[m][r] + eev;
                        float d  = t1 - 2.0f * acc[m][n][r];
                        bool lt1 = d < sd1[m][r];
                        bool lt2 = d < sd2[m][r];
                        sd2[m][r] = lt1 ? sd1[m][r] : (lt2 ? d : sd2[m][r]);
                        if (lt1) { sd1[m][r] = d; sj1[m][r] = code; }
                    }
            }
        }
    }

    // ---- cross-lane top-2 merge over the 16 code-lanes ----
    #pragma unroll
    for (int off = 1; off <= 8; off <<= 1) {
        #pragma unroll
        for (int m = 0; m < 4; ++m)
            #pragma unroll
            for (int r = 0; r < 4; ++r) {
                float od1 = __shfl_xor(sd1[m][r], off);
                int   oj1 = __shfl_xor(sj1[m][r], off);
                float od2 = __shfl_xor(sd2[m][r], off);
                float nd2 = fminf(fmaxf(sd1[m][r], od1), fminf(sd2[m][r], od2));
                bool tk = (od1 < sd1[m][r]) || (od1 == sd1[m][r] && oj1 < sj1[m][r]);
                if (tk) { sd1[m][r] = od1; sj1[m][r] = oj1; }
                sd2[m][r] = nd2;
            }
    }
    if (lr == 0) {
        #pragma unroll
        for (int m = 0; m < 4; ++m)
            #pragma unroll
            for (int r = 0; r < 4; ++r) {
                int tok = m * 16 + lg * 4 + r;
                rd1[wn * 64 + tok] = sd1[m][r];
                rj1[wn * 64 + tok] = sj1[m][r];
                rd2[wn * 64 + tok] = sd2[m][r];
            }
    }
    __syncthreads();

    // ---- combine 8 waves, decide, emit idx / flag / zz ----
    if (tid < 64) {
        float d1f = rd1[tid]; int j1f = rj1[tid]; float d2f = rd2[tid];
        #pragma unroll
        for (int w = 1; w < 8; ++w) {
            float od1 = rd1[w * 64 + tid];
            int   oj1 = rj1[w * 64 + tid];
            float od2 = rd2[w * 64 + tid];
            float nd2 = fminf(fmaxf(d1f, od1), fminf(d2f, od2));
            bool tk = (od1 < d1f) || (od1 == d1f && oj1 < j1f);
            if (tk) { d1f = od1; j1f = oj1; }
            d2f = nd2;
        }
        rbj[tid] = j1f;
        int gtok = b * HW + hw0 + tid;
        out[(size_t)ZQ_SIZE + gtok] = (float)j1f;
        zzw[gtok] = zzp[2 * tid] + zzp[2 * tid + 1];
        if (!(d2f - d1f > MARGIN)) {
            int slot = atomicAdd(cnt, 1);
            list[slot] = gtok;
        }
    }
    __syncthreads();

    // ---- z_q: gather emb rows -> LDS (aliases slab area) -> coalesced NCHW ----
    float* zq_st = (float*)arena;   // [64][260]
    {
        int row = tid >> 3, sub = tid & 7;
        int j = rbj[row];
        const float* er = emb + (size_t)j * CDIM;
        #pragma unroll
        for (int i = 0; i < 8; ++i) {
            int c = (sub << 2) + (i << 5);
            float4 v = *reinterpret_cast<const float4*>(er + c);
            *reinterpret_cast<float4*>(&zq_st[row * 260 + c]) = v;
        }
    }
    __syncthreads();
    {
        int tok = tid & 63, cg = tid >> 6;
        float* ob = out + (size_t)b * CDIM * HW + hw0 + tok;
        #pragma unroll 4
        for (int i = 0; i < 32; ++i) {
            int c = (cg << 5) + i;
            ob[(size_t)c * HW] = zq_st[tok * 260 + c];
        }
    }
}

// ---------------- exact fp32 fallback (float4 loads, same fmaf order) ----------------
__global__ __launch_bounds__(256) void vq_fallback(const float* __restrict__ z,
                                                   const float* __restrict__ emb,
                                                   const float* __restrict__ eew,
                                                   const float* __restrict__ zzw,
                                                   const int* __restrict__ cnt,
                                                   const int* __restrict__ list,
                                                   float* __restrict__ out) {
    __shared__ __align__(16) float elds[64 * 260];
    __shared__ float zrow[4][256];
    __shared__ int   toks[4];

    const int tid  = threadIdx.x;
    const int lane = tid & 63;
    const int wv   = tid >> 6;
    const int nt   = *cnt;
    const int groups = (nt + 3) >> 2;

    for (int g = blockIdx.x; g < groups; g += gridDim.x) {
        if (tid < 4) toks[tid] = (g * 4 + tid < nt) ? list[g * 4 + tid] : -1;
        __syncthreads();
        const int gt  = toks[wv];
        const bool act = gt >= 0;
        const int tb  = act ? (gt >> 12) : 0;
        const int thw = act ? (gt & 4095) : 0;
        if (act) {
            #pragma unroll
            for (int i = 0; i < 4; ++i)
                zrow[wv][i * 64 + lane] = z[(size_t)tb * CDIM * HW + (size_t)(i * 64 + lane) * HW + thw];
        }
        const float zz = act ? zzw[gt] : 0.0f;
        float d1 = INFINITY; int j1 = NE;

        for (int c = 0; c < 16; ++c) {
            __syncthreads();
            {
                int row = tid >> 2, sub = tid & 3;
                #pragma unroll
                for (int i = 0; i < 16; ++i) {
                    int col = (sub << 2) + (i << 4);
                    float4 v = *reinterpret_cast<const float4*>(
                        &emb[(size_t)(c * 64 + row) * CDIM + col]);
                    *reinterpret_cast<float4*>(&elds[row * 260 + col]) = v;
                }
            }
            __syncthreads();
            if (act) {
                float acc = 0.0f;
                #pragma unroll 8
                for (int kq = 0; kq < 64; ++kq) {
                    float4 ev = *reinterpret_cast<const float4*>(&elds[lane * 260 + kq * 4]);
                    float4 zv = *reinterpret_cast<const float4*>(&zrow[wv][kq * 4]);
                    acc = fmaf(zv.x, ev.x, acc);
                    acc = fmaf(zv.y, ev.y, acc);
                    acc = fmaf(zv.z, ev.z, acc);
                    acc = fmaf(zv.w, ev.w, acc);
                }
                int j = c * 64 + lane;
                float t1 = zz + eew[j];
                float d  = t1 - 2.0f * acc;
                if (d < d1) { d1 = d; j1 = j; }
            }
        }
        #pragma unroll
        for (int off = 1; off <= 32; off <<= 1) {
            float od = __shfl_xor(d1, off);
            int   oj = __shfl_xor(j1, off);
            if (od < d1 || (od == d1 && oj < j1)) { d1 = od; j1 = oj; }
        }
        if (act) {
            if (lane == 0) out[(size_t)ZQ_SIZE + gt] = (float)j1;
            #pragma unroll
            for (int i = 0; i < 4; ++i) {
                int cc = i * 64 + lane;
                out[(size_t)tb * CDIM * HW + (size_t)cc * HW + thw] = emb[(size_t)j1 * CDIM + cc];
            }
        }
        __syncthreads();
    }
}

// ---------------- legacy round-1 kernel (only if ws too small) ----------------
#define BM 32
#define BN 256
#define BK 16
__global__ __launch_bounds__(256, 3) void vq_legacy(const float* __restrict__ z,
                                                    const float* __restrict__ emb,
                                                    const float* __restrict__ ee,
                                                    float* __restrict__ out) {
    __shared__ float zs[CDIM][BM];
    __shared__ float es[BK][BN];
    __shared__ float ees[BN];
    __shared__ float zzs[BM];
    __shared__ float red_d[4][BM];
    __shared__ int   red_j[4][BM];
    __shared__ int   bestj_s[BM];

    const int tid = threadIdx.x;
    const int b   = blockIdx.x >> 7;
    const int hw0 = (blockIdx.x & 127) << 5;
    const int ti  = tid & 7;
    const int tj  = tid >> 3;
    const int tm0 = ti << 2;
    const int jc0 = tj << 3;
    {
        const float* zb = z + (size_t)b * CDIM * HW + hw0;
        #pragma unroll
        for (int r = 0; r < 8; ++r) {
            int f4 = (r << 8) + tid;
            int c  = f4 >> 3;
            int t4 = (f4 & 7) << 2;
            float4 v = *reinterpret_cast<const float4*>(zb + (size_t)c * HW + t4);
            *reinterpret_cast<float4*>(&zs[c][t4]) = v;
        }
    }
    __syncthreads();
    if (tid < BM) zzs[tid] = pairwise256_sq([&](int i) { return zs[i][tid]; });
    __syncthreads();
    float bd[4]; int bj[4];
    #pragma unroll
    for (int i = 0; i < 4; ++i) { bd[i] = INFINITY; bj[i] = NE; }
    for (int jt = 0; jt < NE / BN; ++jt) {
        const int j0 = jt * BN;
        float acc[4][8];
        #pragma unroll
        for (int i = 0; i < 4; ++i)
            #pragma unroll
            for (int jj = 0; jj < 8; ++jj) acc[i][jj] = 0.0f;
        for (int kt = 0; kt < CDIM / BK; ++kt) {
            __syncthreads();
            #pragma unroll
            for (int r = 0; r < 4; ++r) {
                int f4 = (r << 8) + tid;
                int jj = f4 >> 2;
                int c4 = (f4 & 3) << 2;
                float4 v = *reinterpret_cast<const float4*>(
                    emb + (size_t)(j0 + jj) * CDIM + kt * BK + c4);
                es[c4 + 0][jj] = v.x; es[c4 + 1][jj] = v.y;
                es[c4 + 2][jj] = v.z; es[c4 + 3][jj] = v.w;
            }
            if (kt == 0 && tid < BN) ees[tid] = ee[j0 + tid];
            __syncthreads();
            #pragma unroll
            for (int k = 0; k < BK; ++k) {
                float4 av  = *reinterpret_cast<const float4*>(&zs[kt * BK + k][tm0]);
                float4 bv0 = *reinterpret_cast<const float4*>(&es[k][jc0]);
                float4 bv1 = *reinterpret_cast<const float4*>(&es[k][jc0 + 4]);
                float bb[8] = {bv0.x, bv0.y, bv0.z, bv0.w, bv1.x, bv1.y, bv1.z, bv1.w};
                #pragma unroll
                for (int jj = 0; jj < 8; ++jj) {
                    acc[0][jj] = fmaf(av.x, bb[jj], acc[0][jj]);
                    acc[1][jj] = fmaf(av.y, bb[jj], acc[1][jj]);
                    acc[2][jj] = fmaf(av.z, bb[jj], acc[2][jj]);
                    acc[3][jj] = fmaf(av.w, bb[jj], acc[3][jj]);
                }
            }
        }
        #pragma unroll
        for (int i = 0; i < 4; ++i) {
            float zzv = zzs[tm0 + i];
            #pragma unroll
            for (int jj = 0; jj < 8; ++jj) {
                float t1 = zzv + ees[jc0 + jj];
                float d  = t1 - 2.0f * acc[i][jj];
                if (d < bd[i]) { bd[i] = d; bj[i] = j0 + jc0 + jj; }
            }
        }
    }
    #pragma unroll
    for (int off = 8; off <= 32; off <<= 1) {
        #pragma unroll
        for (int i = 0; i < 4; ++i) {
            float od = __shfl_xor(bd[i], off);
            int   oj = __shfl_xor(bj[i], off);
            if (od < bd[i] || (od == bd[i] && oj < bj[i])) { bd[i] = od; bj[i] = oj; }
        }
    }
    {
        const int lane = tid & 63;
        const int w    = tid >> 6;
        if (lane < 8) {
            #pragma unroll
            for (int i = 0; i < 4; ++i) {
                red_d[w][lane * 4 + i] = bd[i];
                red_j[w][lane * 4 + i] = bj[i];
            }
        }
    }
    __syncthreads();
    if (tid < BM) {
        float d = red_d[0][tid]; int j = red_j[0][tid];
        #pragma unroll
        for (int w2 = 1; w2 < 4; ++w2) {
            float od = red_d[w2][tid]; int oj = red_j[w2][tid];
            if (od < d || (od == d && oj < j)) { d = od; j = oj; }
        }
        bestj_s[tid] = j;
        out[(size_t)ZQ_SIZE + (size_t)b * HW + hw0 + tid] = (float)j;
    }
    __syncthreads();
    {
        const int t  = tid & 31;
        const int c0 = tid >> 5;
        const int jb = bestj_s[t];
        const float* er = emb + (size_t)jb * CDIM;
        float* ob = out + (size_t)b * CDIM * HW + hw0 + t;
        #pragma unroll
        for (int c = c0; c < CDIM; c += 8) ob[(size_t)c * HW] = er[c];
    }
}

extern "C" void kernel_launch(void* const* d_in, const int* in_sizes, int n_in,
                              void* d_out, int out_size, void* d_ws, size_t ws_size,
                              hipStream_t stream) {
    const float* z   = (const float*)d_in[0];
    const float* emb = (const float*)d_in[1];
    float* out = (float*)d_out;
    char*  ws  = (char*)d_ws;

    float* ee   = (float*)(ws + WS_EE);
    float* zzw  = (float*)(ws + WS_ZZ);
    int*   cnt  = (int*)  (ws + WS_CNT);
    int*   list = (int*)  (ws + WS_LIST);

    if (ws_size >= (size_t)WS_NEEDED) {
        ee_kernel<<<dim3(NE / 256), dim3(256), 0, stream>>>(emb, ee, cnt);
        vq_main<<<dim3((NB * HW) / 64), dim3(512), 0, stream>>>(z, emb, ee, zzw,
                                                                cnt, list, out);
        vq_fallback<<<dim3(512), dim3(256), 0, stream>>>(z, emb, ee, zzw, cnt, list, out);
    } else {
        ee_kernel<<<dim3(NE / 256), dim3(256), 0, stream>>>(emb, ee, cnt);
        vq_legacy<<<dim3((NB * HW) / BM), dim3(256), 0, stream>>>(z, emb, ee, out);
    }
}

// Round 6
// 238.753 us; speedup vs baseline: 5.0293x; 1.4906x over previous
//
#include <hip/hip_runtime.h>
#include <hip/hip_fp16.h>
#include <math.h>

#define CDIM 256
#define NE   1024
#define HW   4096            // 64*64
#define NB   16
#define ZQ_SIZE (NB*CDIM*HW) // 16777216

typedef unsigned short ushort_t;
typedef __attribute__((ext_vector_type(8))) _Float16 f16x8;
typedef __attribute__((ext_vector_type(8))) unsigned short u16x8;
typedef __attribute__((ext_vector_type(4))) float f32x4;

#define AS1 __attribute__((address_space(1)))
#define AS3 __attribute__((address_space(3)))

// fp16 1-pass dot err sigma ~3.1e-6 << fp32 d-grid (ulp(256)=3.05e-5).
// Unflagged requires measured gap > 1e-4 (>= 4 grid steps); per-d jitter
// vs the validated fp32 chain is <= 1 step unless err > 10 sigma. Safe.
#define MARGIN 1.0e-4f

// ws layout (bytes)
#define WS_EE    0           // 1024 f32
#define WS_ZZ    4096        // 65536 f32
#define WS_CNT   266240      // 1 int (+pad)
#define WS_LIST  266496      // 65536 int
#define WS_ESWZ  528640      // 16 slabs x 32768 B fp16 fragment-major
#define WS_NEEDED 1052928

// ---------------- helpers (validated rounds 1-5) ----------------
__device__ __forceinline__ float sq_nofma(float v) {
    float v2 = v * v;
    asm volatile("" : "+v"(v2));
    return v2;
}

template <typename F>
__device__ __forceinline__ float pairwise256_sq(F get) {
    float total = 0.0f;
    #pragma unroll
    for (int h = 0; h < 2; ++h) {
        float r[8];
        #pragma unroll
        for (int j = 0; j < 8; ++j) r[j] = sq_nofma(get(h * 128 + j));
        #pragma unroll
        for (int i = 8; i < 128; i += 8) {
            #pragma unroll
            for (int j = 0; j < 8; ++j) r[j] += sq_nofma(get(h * 128 + i + j));
        }
        float s = ((r[0] + r[1]) + (r[2] + r[3])) + ((r[4] + r[5]) + (r[6] + r[7]));
        total = (h == 0) ? s : (total + s);
    }
    return total;
}

template <typename F>
__device__ __forceinline__ float pairwise128_sq(F get) {
    float r[8];
    #pragma unroll
    for (int j = 0; j < 8; ++j) r[j] = sq_nofma(get(j));
    #pragma unroll
    for (int i = 8; i < 128; i += 8) {
        #pragma unroll
        for (int j = 0; j < 8; ++j) r[j] += sq_nofma(get(i + j));
    }
    return ((r[0] + r[1]) + (r[2] + r[3])) + ((r[4] + r[5]) + (r[6] + r[7]));
}

__device__ __forceinline__ ushort_t f2h(float v) {
    return __half_as_ushort(__float2half(v));   // v_cvt_f16_f32, RNE
}

// ||emb_j||^2 -> ws; zero flag counter
__global__ __launch_bounds__(256) void ee_kernel(const float* __restrict__ emb,
                                                 float* __restrict__ ee,
                                                 int* __restrict__ cnt) {
    if (blockIdx.x == 0 && threadIdx.x == 0) *cnt = 0;
    int j = blockIdx.x * 256 + threadIdx.x;
    const float* row = emb + (size_t)j * CDIM;
    ee[j] = pairwise256_sq([&](int i) { return row[i]; });
}

// emb fp32 -> fp16, written in per-slab FRAGMENT-MAJOR order so that
// vq_main can stage a slab with linear global_load_lds and read fragments
// at frag_base + lane*16 (conflict-free).
// slab s (chunk=s>>2, kb=s&3), frag f=((wn*2+ks)*2+n), lane=lg*16+lr:
//   element (code = chunk*256 + wn*32 + n*16 + lr, k = kb*64 + ks*32 + lg*8 + e)
//   at byte s*32768 + f*1024 + lane*16 + e*2.
__global__ __launch_bounds__(256) void ecvt_kernel(const float* __restrict__ emb,
                                                   ushort_t* __restrict__ eswz) {
    int g = blockIdx.x * 256 + threadIdx.x;   // 32768 threads
    int s  = g >> 11;          // slab
    int r  = g & 2047;
    int cw = r >> 3;           // code within chunk 0..255
    int kg = r & 7;            // k-group of 8 within slab
    int chunk = s >> 2, kb = s & 3;
    int wn = cw >> 5, n = (cw >> 4) & 1, lr = cw & 15;
    int ks = kg >> 2, lg = kg & 3;

    const float* src = emb + (size_t)(chunk * 256 + cw) * CDIM + kb * 64 + kg * 8;
    float4 a = *reinterpret_cast<const float4*>(src);
    float4 b = *reinterpret_cast<const float4*>(src + 4);
    u16x8 p = { f2h(a.x), f2h(a.y), f2h(a.z), f2h(a.w),
                f2h(b.x), f2h(b.y), f2h(b.z), f2h(b.w) };
    int f = (wn * 2 + ks) * 2 + n;
    size_t dst = (size_t)s * 32768 + f * 1024 + (lg * 16 + lr) * 16;
    *reinterpret_cast<u16x8*>((char*)eswz + dst) = p;
}

// ---------------- main MFMA kernel: 512 thr, 8 waves, 64 tokens, 1-pass fp16 ----------------
__global__ __launch_bounds__(512, 4) void vq_main(const float* __restrict__ z,
                                                  const float* __restrict__ emb,
                                                  const ushort_t* __restrict__ eswz,
                                                  const float* __restrict__ eew,
                                                  float* __restrict__ zzw,
                                                  int* __restrict__ cnt,
                                                  int* __restrict__ list,
                                                  float* __restrict__ out) {
    __shared__ __align__(16) char arena[76544];
    char*  zfB = arena;                     // 32768: z fp16 fragment-major
    char*  esB = arena + 32768;             // 32768: E slab fragment-major
    float* eel = (float*)(arena + 65536);   // 1024 f32
    float* zzp = (float*)(arena + 69632);   // 64x2 f32 halves
    float* rd1 = (float*)(arena + 70144);   // [8][64]
    int*   rj1 = (int*)  (arena + 72192);
    float* rd2 = (float*)(arena + 74240);
    int*   rbj = (int*)  (arena + 76288);   // 64

    const int tid  = threadIdx.x;
    const int lane = tid & 63;
    const int wn   = tid >> 6;              // wave 0..7
    const int b    = blockIdx.x >> 6;
    const int hw0  = (blockIdx.x & 63) << 6;
    const float* zb = z + (size_t)b * CDIM * HW + hw0;
    const int lr = lane & 15;
    const int lg = lane >> 4;
    const int laneoff = lane << 4;

    // ---- prologue: z -> fp16 frag-major, eel, zz halves, slab-0 issue ----
    {
        const int tok = lane;
        #pragma unroll
        for (int i = 0; i < 4; ++i) {
            int kg = (wn << 2) + i;          // 0..31
            int k0 = kg << 3;
            u16x8 p;
            #pragma unroll
            for (int e = 0; e < 8; ++e)
                p[e] = f2h(zb[(size_t)(k0 + e) * HW + tok]);
            int m = tok >> 4, lrr = tok & 15;
            int kb_ = kg >> 3, ks_ = (kg >> 2) & 1, lg_ = kg & 3;
            int off = (((kb_ * 2 + ks_) * 4 + m) << 10) + ((lg_ * 16 + lrr) << 4);
            *(u16x8*)(zfB + off) = p;
        }
        eel[tid]       = eew[tid];
        eel[tid + 512] = eew[tid + 512];
    }
    if (tid < 128) {   // exact numpy-pairwise halves
        int tok = tid >> 1, h = tid & 1;
        zzp[tok * 2 + h] = pairwise128_sq([&](int i) {
            return zb[(size_t)(h * 128 + i) * HW + tok];
        });
    }
    {
        const char* gsrc = (const char*)eswz;   // slab 0
        #pragma unroll
        for (int q = 0; q < 4; ++q) {
            __builtin_amdgcn_global_load_lds(
                (const AS1 unsigned*)(gsrc + (q << 13) + (tid << 4)),
                (AS3 unsigned*)(esB + (q << 13) + (wn << 10)), 16, 0, 0);
        }
    }
    asm volatile("s_waitcnt vmcnt(0)" ::: "memory");
    __syncthreads();

    f32x4 acc[4][2];
    float sd1[4][4], sd2[4][4];
    int   sj1[4][4];
    #pragma unroll
    for (int m = 0; m < 4; ++m)
        #pragma unroll
        for (int r = 0; r < 4; ++r) { sd1[m][r] = INFINITY; sd2[m][r] = INFINITY; sj1[m][r] = NE; }

    for (int s = 0; s < 16; ++s) {
        const int chunk = s >> 2, kb = s & 3;
        if (kb == 0) {
            #pragma unroll
            for (int m = 0; m < 4; ++m)
                #pragma unroll
                for (int n = 0; n < 2; ++n) acc[m][n] = (f32x4){0.f, 0.f, 0.f, 0.f};
        }
        #pragma unroll
        for (int ks = 0; ks < 2; ++ks) {
            f16x8 ah[4], bh[2];
            const int fa = (kb * 2 + ks) * 4;
            #pragma unroll
            for (int m = 0; m < 4; ++m)
                ah[m] = *(const f16x8*)(zfB + ((fa + m) << 10) + laneoff);
            const int fb = (wn * 2 + ks) * 2;
            #pragma unroll
            for (int n = 0; n < 2; ++n)
                bh[n] = *(const f16x8*)(esB + ((fb + n) << 10) + laneoff);
            #pragma unroll
            for (int m = 0; m < 4; ++m)
                #pragma unroll
                for (int n = 0; n < 2; ++n)
                    acc[m][n] = __builtin_amdgcn_mfma_f32_16x16x32_f16(ah[m], bh[n], acc[m][n], 0, 0, 0);
        }
        if (kb == 3) {   // chunk epilogue: d = fl(fl(zz+ee) - fl(2*dot)), top-2
            #pragma unroll
            for (int m = 0; m < 4; ++m)
                #pragma unroll
                for (int r = 0; r < 4; ++r) {
                    int t = m * 16 + lg * 4 + r;
                    float zzv = zzp[2 * t] + zzp[2 * t + 1];
                    #pragma unroll
                    for (int n = 0; n < 2; ++n) {
                        int code = (chunk << 8) + (wn << 5) + (n << 4) + lr;
                        float t1 = zzv + eel[code];
                        float d  = t1 - 2.0f * acc[m][n][r];
                        bool lt1 = d < sd1[m][r];
                        bool lt2 = d < sd2[m][r];
                        sd2[m][r] = lt1 ? sd1[m][r] : (lt2 ? d : sd2[m][r]);
                        if (lt1) { sd1[m][r] = d; sj1[m][r] = code; }
                    }
                }
        }
        __syncthreads();           // all waves done reading slab s
        if (s < 15) {
            const char* gsrc = (const char*)eswz + (size_t)(s + 1) * 32768;
            #pragma unroll
            for (int q = 0; q < 4; ++q) {
                __builtin_amdgcn_global_load_lds(
                    (const AS1 unsigned*)(gsrc + (q << 13) + (tid << 4)),
                    (AS3 unsigned*)(esB + (q << 13) + (wn << 10)), 16, 0, 0);
            }
        }
        asm volatile("s_waitcnt vmcnt(0)" ::: "memory");
        __syncthreads();           // slab s+1 ready
    }

    // ---- cross-lane top-2 merge over the 16 code-lanes ----
    #pragma unroll
    for (int off = 1; off <= 8; off <<= 1) {
        #pragma unroll
        for (int m = 0; m < 4; ++m)
            #pragma unroll
            for (int r = 0; r < 4; ++r) {
                float od1 = __shfl_xor(sd1[m][r], off);
                int   oj1 = __shfl_xor(sj1[m][r], off);
                float od2 = __shfl_xor(sd2[m][r], off);
                float nd2 = fminf(fmaxf(sd1[m][r], od1), fminf(sd2[m][r], od2));
                bool tk = (od1 < sd1[m][r]) || (od1 == sd1[m][r] && oj1 < sj1[m][r]);
                if (tk) { sd1[m][r] = od1; sj1[m][r] = oj1; }
                sd2[m][r] = nd2;
            }
    }
    if (lr == 0) {
        #pragma unroll
        for (int m = 0; m < 4; ++m)
            #pragma unroll
            for (int r = 0; r < 4; ++r) {
                int tok = m * 16 + lg * 4 + r;
                rd1[wn * 64 + tok] = sd1[m][r];
                rj1[wn * 64 + tok] = sj1[m][r];
                rd2[wn * 64 + tok] = sd2[m][r];
            }
    }
    __syncthreads();

    // ---- combine 8 waves, decide, emit idx / flag / zz ----
    if (tid < 64) {
        float d1f = rd1[tid]; int j1f = rj1[tid]; float d2f = rd2[tid];
        #pragma unroll
        for (int w = 1; w < 8; ++w) {
            float od1 = rd1[w * 64 + tid];
            int   oj1 = rj1[w * 64 + tid];
            float od2 = rd2[w * 64 + tid];
            float nd2 = fminf(fmaxf(d1f, od1), fminf(d2f, od2));
            bool tk = (od1 < d1f) || (od1 == d1f && oj1 < j1f);
            if (tk) { d1f = od1; j1f = oj1; }
            d2f = nd2;
        }
        rbj[tid] = j1f;
        int gtok = b * HW + hw0 + tid;
        out[(size_t)ZQ_SIZE + gtok] = (float)j1f;
        zzw[gtok] = zzp[2 * tid] + zzp[2 * tid + 1];
        if (!(d2f - d1f > MARGIN)) {
            int slot = atomicAdd(cnt, 1);
            list[slot] = gtok;
        }
    }
    __syncthreads();

    // ---- z_q: gather emb rows -> LDS -> coalesced NCHW ----
    float* zq_st = (float*)arena;   // [64][260]
    {
        int row = tid >> 3, sub = tid & 7;
        int j = rbj[row];
        const float* er = emb + (size_t)j * CDIM;
        #pragma unroll
        for (int i = 0; i < 8; ++i) {
            int c = (sub << 2) + (i << 5);
            float4 v = *reinterpret_cast<const float4*>(er + c);
            *reinterpret_cast<float4*>(&zq_st[row * 260 + c]) = v;
        }
    }
    __syncthreads();
    {
        int tok = tid & 63, cg = tid >> 6;
        float* ob = out + (size_t)b * CDIM * HW + hw0 + tok;
        #pragma unroll 4
        for (int i = 0; i < 32; ++i) {
            int c = (cg << 5) + i;
            ob[(size_t)c * HW] = zq_st[tok * 260 + c];
        }
    }
}

// ---------------- exact fp32 fallback (validated round 5, unchanged) ----------------
__global__ __launch_bounds__(256) void vq_fallback(const float* __restrict__ z,
                                                   const float* __restrict__ emb,
                                                   const float* __restrict__ eew,
                                                   const float* __restrict__ zzw,
                                                   const int* __restrict__ cnt,
                                                   const int* __restrict__ list,
                                                   float* __restrict__ out) {
    __shared__ __align__(16) float elds[64 * 260];
    __shared__ float zrow[4][256];
    __shared__ int   toks[4];

    const int tid  = threadIdx.x;
    const int lane = tid & 63;
    const int wv   = tid >> 6;
    const int nt   = *cnt;
    const int groups = (nt + 3) >> 2;

    for (int g = blockIdx.x; g < groups; g += gridDim.x) {
        if (tid < 4) toks[tid] = (g * 4 + tid < nt) ? list[g * 4 + tid] : -1;
        __syncthreads();
        const int gt  = toks[wv];
        const bool act = gt >= 0;
        const int tb  = act ? (gt >> 12) : 0;
        const int thw = act ? (gt & 4095) : 0;
        if (act) {
            #pragma unroll
            for (int i = 0; i < 4; ++i)
                zrow[wv][i * 64 + lane] = z[(size_t)tb * CDIM * HW + (size_t)(i * 64 + lane) * HW + thw];
        }
        const float zz = act ? zzw[gt] : 0.0f;
        float d1 = INFINITY; int j1 = NE;

        for (int c = 0; c < 16; ++c) {
            __syncthreads();
            {
                int row = tid >> 2, sub = tid & 3;
                #pragma unroll
                for (int i = 0; i < 16; ++i) {
                    int col = (sub << 2) + (i << 4);
                    float4 v = *reinterpret_cast<const float4*>(
                        &emb[(size_t)(c * 64 + row) * CDIM + col]);
                    *reinterpret_cast<float4*>(&elds[row * 260 + col]) = v;
                }
            }
            __syncthreads();
            if (act) {
                float acc = 0.0f;
                #pragma unroll 8
                for (int kq = 0; kq < 64; ++kq) {
                    float4 ev = *reinterpret_cast<const float4*>(&elds[lane * 260 + kq * 4]);
                    float4 zv = *reinterpret_cast<const float4*>(&zrow[wv][kq * 4]);
                    acc = fmaf(zv.x, ev.x, acc);
                    acc = fmaf(zv.y, ev.y, acc);
                    acc = fmaf(zv.z, ev.z, acc);
                    acc = fmaf(zv.w, ev.w, acc);
                }
                int j = c * 64 + lane;
                float t1 = zz + eew[j];
                float d  = t1 - 2.0f * acc;
                if (d < d1) { d1 = d; j1 = j; }
            }
        }
        #pragma unroll
        for (int off = 1; off <= 32; off <<= 1) {
            float od = __shfl_xor(d1, off);
            int   oj = __shfl_xor(j1, off);
            if (od < d1 || (od == d1 && oj < j1)) { d1 = od; j1 = oj; }
        }
        if (act) {
            if (lane == 0) out[(size_t)ZQ_SIZE + gt] = (float)j1;
            #pragma unroll
            for (int i = 0; i < 4; ++i) {
                int cc = i * 64 + lane;
                out[(size_t)tb * CDIM * HW + (size_t)cc * HW + thw] = emb[(size_t)j1 * CDIM + cc];
            }
        }
        __syncthreads();
    }
}

// ---------------- legacy round-1 kernel (only if ws too small) ----------------
#define BM 32
#define BN 256
#define BK 16
__global__ __launch_bounds__(256, 3) void vq_legacy(const float* __restrict__ z,
                                                    const float* __restrict__ emb,
                                                    const float* __restrict__ ee,
                                                    float* __restrict__ out) {
    __shared__ float zs[CDIM][BM];
    __shared__ float es[BK][BN];
    __shared__ float ees[BN];
    __shared__ float zzs[BM];
    __shared__ float red_d[4][BM];
    __shared__ int   red_j[4][BM];
    __shared__ int   bestj_s[BM];

    const int tid = threadIdx.x;
    const int b   = blockIdx.x >> 7;
    const int hw0 = (blockIdx.x & 127) << 5;
    const int ti  = tid & 7;
    const int tj  = tid >> 3;
    const int tm0 = ti << 2;
    const int jc0 = tj << 3;
    {
        const float* zb = z + (size_t)b * CDIM * HW + hw0;
        #pragma unroll
        for (int r = 0; r < 8; ++r) {
            int f4 = (r << 8) + tid;
            int c  = f4 >> 3;
            int t4 = (f4 & 7) << 2;
            float4 v = *reinterpret_cast<const float4*>(zb + (size_t)c * HW + t4);
            *reinterpret_cast<float4*>(&zs[c][t4]) = v;
        }
    }
    __syncthreads();
    if (tid < BM) zzs[tid] = pairwise256_sq([&](int i) { return zs[i][tid]; });
    __syncthreads();
    float bd[4]; int bj[4];
    #pragma unroll
    for (int i = 0; i < 4; ++i) { bd[i] = INFINITY; bj[i] = NE; }
    for (int jt = 0; jt < NE / BN; ++jt) {
        const int j0 = jt * BN;
        float acc[4][8];
        #pragma unroll
        for (int i = 0; i < 4; ++i)
            #pragma unroll
            for (int jj = 0; jj < 8; ++jj) acc[i][jj] = 0.0f;
        for (int kt = 0; kt < CDIM / BK; ++kt) {
            __syncthreads();
            #pragma unroll
            for (int r = 0; r < 4; ++r) {
                int f4 = (r << 8) + tid;
                int jj = f4 >> 2;
                int c4 = (f4 & 3) << 2;
                float4 v = *reinterpret_cast<const float4*>(
                    emb + (size_t)(j0 + jj) * CDIM + kt * BK + c4);
                es[c4 + 0][jj] = v.x; es[c4 + 1][jj] = v.y;
                es[c4 + 2][jj] = v.z; es[c4 + 3][jj] = v.w;
            }
            if (kt == 0 && tid < BN) ees[tid] = ee[j0 + tid];
            __syncthreads();
            #pragma unroll
            for (int k = 0; k < BK; ++k) {
                float4 av  = *reinterpret_cast<const float4*>(&zs[kt * BK + k][tm0]);
                float4 bv0 = *reinterpret_cast<const float4*>(&es[k][jc0]);
                float4 bv1 = *reinterpret_cast<const float4*>(&es[k][jc0 + 4]);
                float bb[8] = {bv0.x, bv0.y, bv0.z, bv0.w, bv1.x, bv1.y, bv1.z, bv1.w};
                #pragma unroll
                for (int jj = 0; jj < 8; ++jj) {
                    acc[0][jj] = fmaf(av.x, bb[jj], acc[0][jj]);
                    acc[1][jj] = fmaf(av.y, bb[jj], acc[1][jj]);
                    acc[2][jj] = fmaf(av.z, bb[jj], acc[2][jj]);
                    acc[3][jj] = fmaf(av.w, bb[jj], acc[3][jj]);
                }
            }
        }
        #pragma unroll
        for (int i = 0; i < 4; ++i) {
            float zzv = zzs[tm0 + i];
            #pragma unroll
            for (int jj = 0; jj < 8; ++jj) {
                float t1 = zzv + ees[jc0 + jj];
                float d  = t1 - 2.0f * acc[i][jj];
                if (d < bd[i]) { bd[i] = d; bj[i] = j0 + jc0 + jj; }
            }
        }
    }
    #pragma unroll
    for (int off = 8; off <= 32; off <<= 1) {
        #pragma unroll
        for (int i = 0; i < 4; ++i) {
            float od = __shfl_xor(bd[i], off);
            int   oj = __shfl_xor(bj[i], off);
            if (od < bd[i] || (od == bd[i] && oj < bj[i])) { bd[i] = od; bj[i] = oj; }
        }
    }
    {
        const int lane = tid & 63;
        const int w    = tid >> 6;
        if (lane < 8) {
            #pragma unroll
            for (int i = 0; i < 4; ++i) {
                red_d[w][lane * 4 + i] = bd[i];
                red_j[w][lane * 4 + i] = bj[i];
            }
        }
    }
    __syncthreads();
    if (tid < BM) {
        float d = red_d[0][tid]; int j = red_j[0][tid];
        #pragma unroll
        for (int w2 = 1; w2 < 4; ++w2) {
            float od = red_d[w2][tid]; int oj = red_j[w2][tid];
            if (od < d || (od == d && oj < j)) { d = od; j = oj; }
        }
        bestj_s[tid] = j;
        out[(size_t)ZQ_SIZE + (size_t)b * HW + hw0 + tid] = (float)j;
    }
    __syncthreads();
    {
        const int t  = tid & 31;
        const int c0 = tid >> 5;
        const int jb = bestj_s[t];
        const float* er = emb + (size_t)jb * CDIM;
        float* ob = out + (size_t)b * CDIM * HW + hw0 + t;
        #pragma unroll
        for (int c = c0; c < CDIM; c += 8) ob[(size_t)c * HW] = er[c];
    }
}

extern "C" void kernel_launch(void* const* d_in, const int* in_sizes, int n_in,
                              void* d_out, int out_size, void* d_ws, size_t ws_size,
                              hipStream_t stream) {
    const float* z   = (const float*)d_in[0];
    const float* emb = (const float*)d_in[1];
    float* out = (float*)d_out;
    char*  ws  = (char*)d_ws;

    float*    ee   = (float*)(ws + WS_EE);
    float*    zzw  = (float*)(ws + WS_ZZ);
    int*      cnt  = (int*)  (ws + WS_CNT);
    int*      list = (int*)  (ws + WS_LIST);
    ushort_t* eswz = (ushort_t*)(ws + WS_ESWZ);

    if (ws_size >= (size_t)WS_NEEDED) {
        ee_kernel<<<dim3(NE / 256), dim3(256), 0, stream>>>(emb, ee, cnt);
        ecvt_kernel<<<dim3(128), dim3(256), 0, stream>>>(emb, eswz);
        vq_main<<<dim3((NB * HW) / 64), dim3(512), 0, stream>>>(z, emb, eswz, ee, zzw,
                                                                cnt, list, out);
        vq_fallback<<<dim3(512), dim3(256), 0, stream>>>(z, emb, ee, zzw, cnt, list, out);
    } else {
        ee_kernel<<<dim3(NE / 256), dim3(256), 0, stream>>>(emb, ee, cnt);
        vq_legacy<<<dim3((NB * HW) / BM), dim3(256), 0, stream>>>(z, emb, ee, out);
    }
}